// Round 1
// baseline (277.815 us; speedup 1.0000x reference)
//
#include <hip/hip_runtime.h>

// VolumeRenderer: N=65536 rays, L=192 samples.
//   delta[l] = depth[l+1]-depth[l] (last = 1e10)
//   alpha = 1 - exp(-relu(sigma)*delta)
//   w     = alpha * (1 - alpha + 1e-10)        (cumprod over size-1 axis = identity)
//   color = sum_l sigmoid(rgb[l]) * w[l]        -> (N,3)
//   depth_out = sum_l w[l]*depth[l]             -> (N,1)
//
// Memory-bound: 252 MB read / launch -> ~40 us floor at 6.3 TB/s.
// v2: LDS-staged, fully-coalesced float4 global loads (G13). Previous version
// used 15 scalar dword loads/wave (stride-3 on rgb) and achieved only 2.65 TB/s.

constexpr int L = 192;
constexpr int RPB = 4;   // rays per block = waves per block (wave64 = one ray)

__device__ __forceinline__ float fast_sigmoid(float x) {
    return __builtin_amdgcn_rcpf(1.0f + __expf(-x));
}

__global__ __launch_bounds__(256) void volrender_kernel(
    const float* __restrict__ depth, const float* __restrict__ rgb,
    const float* __restrict__ sigma, float* __restrict__ out, int n_rays)
{
    // +4 pad so the dp[idx+1] read for the last sample of the last ray stays in-bounds
    __shared__ float s_depth[RPB * L + 4];   // 772 floats
    __shared__ float s_sigma[RPB * L];       // 768 floats
    __shared__ float s_rgb[RPB * L * 3];     // 2304 floats
    // total 15.4 KB -> 8 blocks/CU (thread-limited, not LDS-limited)

    const int tid = threadIdx.x;
    const int r0  = blockIdx.x * RPB;

    // ---- cooperative, fully-coalesced float4 staging ----
    // block's regions are contiguous: depth/sigma 192 float4 each, rgb 576 float4
    const float4* gd = (const float4*)(depth + (long long)r0 * L);
    const float4* gs = (const float4*)(sigma + (long long)r0 * L);
    const float4* gc = (const float4*)(rgb   + (long long)r0 * L * 3);

    float4* sd4 = (float4*)s_depth;
    float4* ss4 = (float4*)s_sigma;
    float4* sc4 = (float4*)s_rgb;

    sc4[tid]       = gc[tid];
    sc4[tid + 256] = gc[tid + 256];
    if (tid < 64) sc4[tid + 512] = gc[tid + 512];
    if (tid < 192) {
        sd4[tid] = gd[tid];
        ss4[tid] = gs[tid];
    }
    __syncthreads();

    // ---- compute phase: wave w handles ray r0+w, lane handles samples l, l+64, l+128 ----
    const int lane = tid & 63;
    const int w    = tid >> 6;
    const int ray  = r0 + w;

    const float* dp = s_depth + w * L;
    const float* sp = s_sigma + w * L;
    const float* cp = s_rgb   + w * L * 3;

    float cr = 0.0f, cg = 0.0f, cb = 0.0f, dd = 0.0f;
    #pragma unroll
    for (int k = 0; k < 3; ++k) {
        const int idx = lane + 64 * k;
        const float d = dp[idx];                       // stride-1: 2-way bank alias, free
        // delta from LDS neighbor (replaces cross-lane shuffles)
        const float dl = (idx == L - 1) ? 1e10f : (dp[idx + 1] - d);
        const float s  = sp[idx];
        const float al = 1.0f - __expf(-fmaxf(s, 0.0f) * dl);
        const float wt = al * (1.0f - al + 1e-10f);
        // stride-3 float reads: banks (3l+c) mod 32, l vs l+32 alias 2-way -> free
        cr += fast_sigmoid(cp[3 * idx + 0]) * wt;
        cg += fast_sigmoid(cp[3 * idx + 1]) * wt;
        cb += fast_sigmoid(cp[3 * idx + 2]) * wt;
        dd += wt * d;
    }

    // ---- wave (64-lane) butterfly reduction ----
    #pragma unroll
    for (int off = 32; off > 0; off >>= 1) {
        cr += __shfl_xor(cr, off);
        cg += __shfl_xor(cg, off);
        cb += __shfl_xor(cb, off);
        dd += __shfl_xor(dd, off);
    }

    if (lane == 0) {
        out[ray * 3 + 0] = cr;
        out[ray * 3 + 1] = cg;
        out[ray * 3 + 2] = cb;
        out[(long long)n_rays * 3 + ray] = dd;  // depth output after color block
    }
}

extern "C" void kernel_launch(void* const* d_in, const int* in_sizes, int n_in,
                              void* d_out, int out_size, void* d_ws, size_t ws_size,
                              hipStream_t stream) {
    const float* depth = (const float*)d_in[0];
    const float* rgb   = (const float*)d_in[1];
    const float* sigma = (const float*)d_in[2];
    float* out = (float*)d_out;
    const int n_rays = in_sizes[0] / L;      // 65536
    const int blocks = n_rays / RPB;         // 16384 blocks of 256 threads
    volrender_kernel<<<blocks, 256, 0, stream>>>(depth, rgb, sigma, out, n_rays);
}

// Round 2
// 277.448 us; speedup vs baseline: 1.0013x; 1.0013x over previous
//
#include <hip/hip_runtime.h>

// VolumeRenderer: N=65536 rays, L=192 samples.
//   delta[l] = depth[l+1]-depth[l] (last = 1e10)
//   alpha = 1 - exp(-relu(sigma)*delta)
//   w     = alpha * (1 - alpha + 1e-10)     (cumprod over size-1 axis = identity)
//   color = sum_l sigmoid(rgb[l]) * w[l]     -> (N,3)
//   depth_out = sum_l w[l]*depth[l]          -> (N,1)
//
// v3: latency-bound fix. v1 (scalar) and v2 (LDS-staged) both ran 97 us with
// VALUBusy 18% / HBM 16% / VGPR 12-16 -> loads were register-starved and
// serialized (load -> waitcnt -> consume chains). This version keeps 5-10
// independent dwordx4 loads in flight per wave: no LDS, no barrier, no
// divergent load paths, depth-2 software pipeline over 4 rays per wave.
//
// Layout: wave = ray. Lane l (l<48) owns samples 4l..4l+3:
//   depth: 48 float4/ray, sigma: 48 float4/ray, rgb: 144 float4/ray (3/lane).
// Lanes 48-63 load clamped duplicates (same cache lines, no extra HBM) and are
// zero-masked in the reduction.

constexpr int L = 192;
constexpr int RPW = 4;   // rays per wave (software-pipelined)

__device__ __forceinline__ float fast_sigmoid(float x) {
    return __builtin_amdgcn_rcpf(1.0f + __expf(-x));
}

__global__ __launch_bounds__(256) void volrender_kernel(
    const float* __restrict__ depth, const float* __restrict__ rgb,
    const float* __restrict__ sigma, float* __restrict__ out, int n_rays)
{
    const int lane = threadIdx.x & 63;
    const int li   = (lane < 47) ? lane : 47;              // clamp idle lanes
    const int wid  = (blockIdx.x << 2) + (threadIdx.x >> 6);
    const int ray0 = wid * RPW;

    const float4* __restrict__ d4p = (const float4*)depth;
    const float4* __restrict__ s4p = (const float4*)sigma;
    const float4* __restrict__ c4p = (const float4*)rgb;

    // double-buffered per-ray payload: 5 float4 = 20 VGPRs per buffer
    float4 d_a, s_a, c0_a, c1_a, c2_a;
    float4 d_b, s_b, c0_b, c1_b, c2_b;

    {   // prologue: ray0 loads (all independent, issued together)
        const int db = ray0 * 48 + li;
        const int cb = ray0 * 144 + 3 * li;
        d_a  = d4p[db];
        s_a  = s4p[db];
        c0_a = c4p[cb];
        c1_a = c4p[cb + 1];
        c2_a = c4p[cb + 2];
    }

    #pragma unroll
    for (int i = 0; i < RPW; ++i) {
        // ---- prefetch next ray before touching current ray's data ----
        if (i + 1 < RPW) {
            const int rn = ray0 + i + 1;
            const int db = rn * 48 + li;
            const int cb = rn * 144 + 3 * li;
            d_b  = d4p[db];
            s_b  = s4p[db];
            c0_b = c4p[cb];
            c1_b = c4p[cb + 1];
            c2_b = c4p[cb + 2];
        }

        // ---- compute current ray ----
        // neighbor's first depth sample = depth[4(l+1)]
        const float dn  = __shfl(d_a.x, lane + 1);
        const float dl0 = d_a.y - d_a.x;
        const float dl1 = d_a.z - d_a.y;
        const float dl2 = d_a.w - d_a.z;
        const float dl3 = (li == 47) ? 1e10f : (dn - d_a.w);

        const float a0 = 1.0f - __expf(-fmaxf(s_a.x, 0.0f) * dl0);
        const float a1 = 1.0f - __expf(-fmaxf(s_a.y, 0.0f) * dl1);
        const float a2 = 1.0f - __expf(-fmaxf(s_a.z, 0.0f) * dl2);
        const float a3 = 1.0f - __expf(-fmaxf(s_a.w, 0.0f) * dl3);
        const float w0 = a0 * (1.0f - a0 + 1e-10f);
        const float w1 = a1 * (1.0f - a1 + 1e-10f);
        const float w2 = a2 * (1.0f - a2 + 1e-10f);
        const float w3 = a3 * (1.0f - a3 + 1e-10f);

        // rgb float4s of lane l: c0=(r0,g0,b0,r1) c1=(g1,b1,r2,g2) c2=(b2,r3,g3,b3)
        float cr = fast_sigmoid(c0_a.x) * w0 + fast_sigmoid(c0_a.w) * w1
                 + fast_sigmoid(c1_a.z) * w2 + fast_sigmoid(c2_a.y) * w3;
        float cg = fast_sigmoid(c0_a.y) * w0 + fast_sigmoid(c1_a.x) * w1
                 + fast_sigmoid(c1_a.w) * w2 + fast_sigmoid(c2_a.z) * w3;
        float cbl= fast_sigmoid(c0_a.z) * w0 + fast_sigmoid(c1_a.y) * w1
                 + fast_sigmoid(c2_a.x) * w2 + fast_sigmoid(c2_a.w) * w3;
        float dd = d_a.x * w0 + d_a.y * w1 + d_a.z * w2 + d_a.w * w3;

        if (lane >= 48) { cr = 0.0f; cg = 0.0f; cbl = 0.0f; dd = 0.0f; }

        // ---- wave butterfly reduction ----
        #pragma unroll
        for (int off = 32; off > 0; off >>= 1) {
            cr  += __shfl_xor(cr, off);
            cg  += __shfl_xor(cg, off);
            cbl += __shfl_xor(cbl, off);
            dd  += __shfl_xor(dd, off);
        }

        if (lane == 0) {
            const int ray = ray0 + i;
            out[ray * 3 + 0] = cr;
            out[ray * 3 + 1] = cg;
            out[ray * 3 + 2] = cbl;
            out[(long long)n_rays * 3 + ray] = dd;   // depth block after color
        }

        // rotate pipeline buffers (register renaming under full unroll)
        d_a = d_b; s_a = s_b; c0_a = c0_b; c1_a = c1_b; c2_a = c2_b;
    }
}

extern "C" void kernel_launch(void* const* d_in, const int* in_sizes, int n_in,
                              void* d_out, int out_size, void* d_ws, size_t ws_size,
                              hipStream_t stream) {
    const float* depth = (const float*)d_in[0];
    const float* rgb   = (const float*)d_in[1];
    const float* sigma = (const float*)d_in[2];
    float* out = (float*)d_out;
    const int n_rays = in_sizes[0] / L;          // 65536
    const int waves  = n_rays / RPW;             // 16384 waves
    const int blocks = waves / 4;                // 4096 blocks x 256 threads
    volrender_kernel<<<blocks, 256, 0, stream>>>(depth, rgb, sigma, out, n_rays);
}